// Round 8
// baseline (193.780 us; speedup 1.0000x reference)
//
#include <hip/hip_runtime.h>

constexpr int B = 512;
constexpr int D = 2048;
constexpr int C = 10000;
constexpr long long ND = (long long)C * D;      // 20,480,000
constexpr int NBLK = 4096;

typedef float vfloat4 __attribute__((ext_vector_type(4)));  // native vec for NT builtins

// ---------------------------------------------------------------------------
// K1: simplest shifted copy, 16B-aligned both sides, NONTEMPORAL loads
// (centers is never re-read from cache; keep it out of L2/L3 so the write
// stream owns the cache). Copies ALL rows; K2 overwrites the touched ones.
// m=0 lane0 writes pw=0 into out[0] -> loss accumulator init for free.
// ---------------------------------------------------------------------------
__global__ __launch_bounds__(256) void copy_kernel(const float* __restrict__ centers,
                                                   float* __restrict__ out) {
    const long long M = ND / 4;                  // 5,120,000 float4s
    const long long stride = (long long)NBLK * 256;
    const int lane = threadIdx.x & 63;
    const vfloat4* __restrict__ src = reinterpret_cast<const vfloat4*>(centers);
    vfloat4*       __restrict__ dst = reinterpret_cast<vfloat4*>(out);

    long long t = (long long)blockIdx.x * 256 + threadIdx.x;
    long long m = t;
    for (; m + 3 * stride < M; m += 4 * stride) {
        long long m0 = m, m1 = m + stride, m2 = m + 2 * stride, m3 = m + 3 * stride;
        vfloat4 v0 = __builtin_nontemporal_load(&src[m0]);
        vfloat4 v1 = __builtin_nontemporal_load(&src[m1]);
        vfloat4 v2 = __builtin_nontemporal_load(&src[m2]);
        vfloat4 v3 = __builtin_nontemporal_load(&src[m3]);
        float pw0 = __shfl_up(v0[3], 1);
        float pw1 = __shfl_up(v1[3], 1);
        float pw2 = __shfl_up(v2[3], 1);
        float pw3 = __shfl_up(v3[3], 1);
        if (lane == 0) {
            pw0 = (m0 > 0) ? centers[4 * m0 - 1] : 0.0f;   // 0 -> loss init
            pw1 = centers[4 * m1 - 1];
            pw2 = centers[4 * m2 - 1];
            pw3 = centers[4 * m3 - 1];
        }
        vfloat4 w0 = {pw0, v0[0], v0[1], v0[2]};
        vfloat4 w1 = {pw1, v1[0], v1[1], v1[2]};
        vfloat4 w2 = {pw2, v2[0], v2[1], v2[2]};
        vfloat4 w3 = {pw3, v3[0], v3[1], v3[2]};
        dst[m0] = w0;
        dst[m1] = w1;
        dst[m2] = w2;
        dst[m3] = w3;
    }
    for (; m < M; m += stride) {
        vfloat4 v = __builtin_nontemporal_load(&src[m]);
        float pw = __shfl_up(v[3], 1);
        if (lane == 0) pw = (m > 0) ? centers[4 * m - 1] : 0.0f;
        vfloat4 w = {pw, v[0], v[1], v[2]};
        dst[m] = w;
    }
    if (t == 0) out[ND] = centers[ND - 1];       // final element
}

// ---------------------------------------------------------------------------
// K2: fused rank + loss + closed-form center-update for touched rows.
// One block per sample; only rank-0 blocks proceed. Runs after K1
// (stream-ordered) and overwrites its rows. One loss atomic per group.
// ---------------------------------------------------------------------------
__global__ void group_kernel(const float* __restrict__ features,
                             const int* __restrict__ labels,
                             const float* __restrict__ centers,
                             float* __restrict__ out) {
    const int i = blockIdx.x;
    __shared__ int sl[B];
    __shared__ int mem[B];
    for (int j = threadIdx.x; j < B; j += blockDim.x) sl[j] = labels[j];
    __syncthreads();
    const int l = sl[i];

    int k = 0;
    bool rank0 = true;                           // block-uniform
    for (int j = 0; j < B; ++j) {
        if (sl[j] == l) {
            if (j < i) { rank0 = false; break; }
            mem[k++] = j;                        // uniform write
        }
    }
    if (!rank0) return;

    const float kc = exp2f(-(float)k);           // 0.5^k
    const float* __restrict__ crow = centers + (long long)l * D;
    float*       __restrict__ orow = out + 1 + (long long)l * D;
    const int tx = threadIdx.x;

    float cv[8], acc[8];
    float lsum = 0.0f;
#pragma unroll
    for (int jj = 0; jj < 8; ++jj) {
        cv[jj]  = crow[tx + jj * 256];
        acc[jj] = kc * cv[jj];
    }
    for (int r = 0; r < k; ++r) {
        const float* __restrict__ frow = features + (long long)mem[r] * D;
        const float coef = exp2f(-(float)(k - r));   // 0.5^(k-r)
#pragma unroll
        for (int jj = 0; jj < 8; ++jj) {
            float fv = frow[tx + jj * 256];
            float d  = fv - cv[jj];
            lsum    += d * d;
            acc[jj] += coef * fv;
        }
    }
#pragma unroll
    for (int jj = 0; jj < 8; ++jj) orow[tx + jj * 256] = acc[jj];

    for (int off = 32; off > 0; off >>= 1) lsum += __shfl_down(lsum, off);
    __shared__ float wsum[4];
    if ((tx & 63) == 0) wsum[tx >> 6] = lsum;
    __syncthreads();
    if (tx == 0) {
        float tot = wsum[0] + wsum[1] + wsum[2] + wsum[3];
        atomicAdd(out, tot * (1.0f / ((float)B * (float)D)));
    }
}

extern "C" void kernel_launch(void* const* d_in, const int* in_sizes, int n_in,
                              void* d_out, int out_size, void* d_ws, size_t ws_size,
                              hipStream_t stream) {
    const float* features = (const float*)d_in[0];
    const int*   labels   = (const int*)d_in[1];
    const float* centers  = (const float*)d_in[2];
    float*       out      = (float*)d_out;

    copy_kernel<<<NBLK, 256, 0, stream>>>(centers, out);
    group_kernel<<<B, 256, 0, stream>>>(features, labels, centers, out);
}